// Round 3
// baseline (168.708 us; speedup 1.0000x reference)
//
#include <hip/hip_runtime.h>

#define NB 8
#define CH 128
#define HV 64
#define WV 64
#define HO 128
#define WO 128
#define KK 9

// ======================= kernel A: attention (softmax) =======================
// v4 (unchanged from round 2): no LDS. Weights are wave-uniform -> scalar
// s_load from global, consumed as SGPR operands by v_fmac. 1 px/thread,
// 512 blocks x 256 threads = 2048 waves (8/CU).
// Residual (att += guide[:, :K]) folded by peeling channels 0..8.
__global__ __launch_bounds__(256)
void la_att(const float* __restrict__ guide,   // [8,128,128,128]
            const float* __restrict__ wconv,   // [9,128]
            const float* __restrict__ bconv,   // [9]
            float* __restrict__ att)           // [8,9,128,128] (workspace)
{
    const int tid = threadIdx.x;
    const int p  = blockIdx.x * 256 + tid;   // pixel index over (b, ho, wo)
    const int wo = p & 127;
    const int ho = (p >> 7) & 127;
    const int b  = p >> 14;

    const float* gpix = guide + ((size_t)b * CH) * (HO * WO) + ho * WO + wo;

    float a[KK];
    #pragma unroll
    for (int k = 0; k < KK; ++k)
        a[k] = bconv[k];                     // uniform -> s_load

    // ---- peeled channels 0..8: conv + residual (a[c] += g), k==c at compile time
    #pragma unroll
    for (int c = 0; c < KK; ++c) {
        float g = gpix[(size_t)c * (HO * WO)];
        #pragma unroll
        for (int k = 0; k < KK; ++k)
            a[k] += g * wconv[k * CH + c];   // uniform index -> SGPR operand
        a[c] += g;
    }

    // ---- channels 9..127: pure conv, weights via scalar pipe (no LDS)
    #pragma unroll 8
    for (int c = KK; c < CH; ++c) {
        float g = gpix[(size_t)c * (HO * WO)];
        #pragma unroll
        for (int k = 0; k < KK; ++k)
            a[k] += g * wconv[k * CH + c];
    }

    float m = a[0];
    #pragma unroll
    for (int k = 1; k < KK; ++k) m = fmaxf(m, a[k]);
    float s = 0.f;
    #pragma unroll
    for (int k = 0; k < KK; ++k) { a[k] = __expf(a[k] - m); s += a[k]; }
    float r = 1.0f / s;

    float* apix = att + ((size_t)b * KK) * (HO * WO) + ho * WO + wo;
    #pragma unroll
    for (int k = 0; k < KK; ++k)
        apix[(size_t)k * (HO * WO)] = a[k] * r;
}

// ======================= kernel B: weighted 3x3 gather =======================
// v5: LDS-free, barrier-free. Exploits I=2 upsampling: the out quad
// (2h,2h+1)x(2w,2w+1) shares ONE 3x3 value window at (h,w). lane = value
// column (WV=64 = wave width). Per channel: 3 coalesced 256B row loads,
// +-1 column neighbors via __shfl_up/down(.,1) whose edge-lane keep-own
// semantics implement the replication clamp for free. 36 att regs/wave.
// wave task = (b, value row h, 16-channel chunk): 8*64*8 = 4096 waves
// = 1024 blocks x 256 thr (16 waves/CU). Waves of one block share (b,h)
// -> att rows hit L1.
#define CHUNK 16
__global__ __launch_bounds__(256)
void la_gather(const float* __restrict__ value,  // [8,128,64,64]
               const float* __restrict__ att,    // [8,9,128,128]
               float* __restrict__ out)          // [8,128,128,128]
{
    const int tid   = threadIdx.x;
    const int lane  = tid & 63;                   // value column w
    const int wid   = blockIdx.x * 4 + (tid >> 6);// 0..4095
    const int chunk = wid & 7;                    // 16-channel chunk
    const int h     = (wid >> 3) & 63;            // value row
    const int b     = wid >> 9;                   // batch

    // att for the 4 out px (2h,2h+1) x (2*lane, 2*lane+1), 9 k each
    float a00[KK], a01[KK], a10[KK], a11[KK];
    {
        const float* ap = att + ((size_t)b * KK * HO + 2 * h) * WO + 2 * lane;
        #pragma unroll
        for (int k = 0; k < KK; ++k) {
            float2 r0 = *(const float2*)(ap + (size_t)k * (HO * WO));
            float2 r1 = *(const float2*)(ap + (size_t)k * (HO * WO) + WO);
            a00[k] = r0.x; a01[k] = r0.y;
            a10[k] = r1.x; a11[k] = r1.y;
        }
    }

    const int hm = (h > 0) ? h - 1 : 0;           // replication clamp, rows
    const int hp = (h < HV - 1) ? h + 1 : HV - 1;
    const float* vc  = value + ((size_t)b * CH + chunk * CHUNK) * (HV * WV) + lane;
    const float* prm = vc + hm * WV;
    const float* pr0 = vc + h  * WV;
    const float* prp = vc + hp * WV;
    float* ob = out + (((size_t)b * CH + chunk * CHUNK) * HO + 2 * h) * WO + 2 * lane;

    #pragma unroll 4
    for (int cc = 0; cc < CHUNK; ++cc) {
        float vm = prm[(size_t)cc * (HV * WV)];
        float v0 = pr0[(size_t)cc * (HV * WV)];
        float vp = prp[(size_t)cc * (HV * WV)];
        // column neighbors; edge lanes keep own value == replication clamp
        float vmL = __shfl_up(vm, 1), vmR = __shfl_down(vm, 1);
        float v0L = __shfl_up(v0, 1), v0R = __shfl_down(v0, 1);
        float vpL = __shfl_up(vp, 1), vpR = __shfl_down(vp, 1);

        float s00 = vmL*a00[0] + vm*a00[1] + vmR*a00[2]
                  + v0L*a00[3] + v0*a00[4] + v0R*a00[5]
                  + vpL*a00[6] + vp*a00[7] + vpR*a00[8];
        float s01 = vmL*a01[0] + vm*a01[1] + vmR*a01[2]
                  + v0L*a01[3] + v0*a01[4] + v0R*a01[5]
                  + vpL*a01[6] + vp*a01[7] + vpR*a01[8];
        float s10 = vmL*a10[0] + vm*a10[1] + vmR*a10[2]
                  + v0L*a10[3] + v0*a10[4] + v0R*a10[5]
                  + vpL*a10[6] + vp*a10[7] + vpR*a10[8];
        float s11 = vmL*a11[0] + vm*a11[1] + vmR*a11[2]
                  + v0L*a11[3] + v0*a11[4] + v0R*a11[5]
                  + vpL*a11[6] + vp*a11[7] + vpR*a11[8];

        float* oc = ob + (size_t)cc * (HO * WO);
        float2 r0; r0.x = s00; r0.y = s01;
        float2 r1; r1.x = s10; r1.y = s11;
        *(float2*)oc        = r0;   // out row 2h
        *(float2*)(oc + WO) = r1;   // out row 2h+1
    }
}

// ================== fallback: proven single fused kernel (R1) ==================
#define CCH 8
__global__ __launch_bounds__(128)
void la_fused(const float* __restrict__ guide,
              const float* __restrict__ value,
              const float* __restrict__ wconv,
              const float* __restrict__ bconv,
              float* __restrict__ out)
{
    __shared__ float s_wT[CH * 12];
    __shared__ float s_haloF[CCH * 110];

    const int tid = threadIdx.x;
    const int blk = blockIdx.x;
    const int wt = blk & 7;
    const int ht = (blk >> 3) & 7;
    const int b  = blk >> 6;

    for (int i = tid; i < KK * CH; i += 128) {
        int k = i >> 7;
        int c = i & 127;
        s_wT[c * 12 + k] = wconv[i];
    }

    const int tlwp = tid & 7;
    const int tho  = tid >> 3;
    const int ho = ht * 16 + tho;
    const int wo = wt * 16 + tlwp * 2;

    const float* gpix = guide + (((size_t)b * CH) * HO + ho) * WO + wo;

    float att0[KK], att1[KK];
    #pragma unroll
    for (int k = 0; k < KK; ++k) {
        float2 g = *(const float2*)(gpix + (size_t)k * (HO * WO));
        float bc = bconv[k];
        att0[k] = bc + g.x;
        att1[k] = bc + g.y;
    }
    __syncthreads();

    #pragma unroll 4
    for (int c = 0; c < CH; ++c) {
        float2 g = *(const float2*)(gpix + (size_t)c * (HO * WO));
        const float4* wt4 = (const float4*)&s_wT[c * 12];
        float4 wa = wt4[0];
        float4 wb = wt4[1];
        float w8 = s_wT[c * 12 + 8];
        att0[0] += g.x * wa.x;  att1[0] += g.y * wa.x;
        att0[1] += g.x * wa.y;  att1[1] += g.y * wa.y;
        att0[2] += g.x * wa.z;  att1[2] += g.y * wa.z;
        att0[3] += g.x * wa.w;  att1[3] += g.y * wa.w;
        att0[4] += g.x * wb.x;  att1[4] += g.y * wb.x;
        att0[5] += g.x * wb.y;  att1[5] += g.y * wb.y;
        att0[6] += g.x * wb.z;  att1[6] += g.y * wb.z;
        att0[7] += g.x * wb.w;  att1[7] += g.y * wb.w;
        att0[8] += g.x * w8;    att1[8] += g.y * w8;
    }

    float m0 = att0[0], m1 = att1[0];
    #pragma unroll
    for (int k = 1; k < KK; ++k) { m0 = fmaxf(m0, att0[k]); m1 = fmaxf(m1, att1[k]); }
    float s0 = 0.f, s1 = 0.f;
    #pragma unroll
    for (int k = 0; k < KK; ++k) {
        att0[k] = __expf(att0[k] - m0); s0 += att0[k];
        att1[k] = __expf(att1[k] - m1); s1 += att1[k];
    }
    float r0 = 1.0f / s0, r1 = 1.0f / s1;
    #pragma unroll
    for (int k = 0; k < KK; ++k) { att0[k] *= r0; att1[k] *= r1; }

    const int h0 = ht * 8 - 1;
    const int w0 = wt * 8 - 1;
    const int lh = tho >> 1;
    const float* vb = value + (size_t)b * CH * (HV * WV);
    float* ob = out + (((size_t)b * CH) * HO + ho) * WO + wo;

    for (int c0 = 0; c0 < CH; c0 += CCH) {
        __syncthreads();
        for (int i = tid; i < CCH * 100; i += 128) {
            int cc = i / 100;
            int r  = i - cc * 100;
            int hr = r / 10;
            int wr = r - hr * 10;
            int hh = min(max(h0 + hr, 0), HV - 1);
            int ww = min(max(w0 + wr, 0), WV - 1);
            s_haloF[cc * 110 + hr * 11 + wr] =
                vb[(size_t)(c0 + cc) * (HV * WV) + hh * WV + ww];
        }
        __syncthreads();
        #pragma unroll
        for (int cc = 0; cc < CCH; ++cc) {
            const float* hp = &s_haloF[cc * 110 + lh * 11 + tlwp];
            float v, q0, q1;
            v = hp[0];  q0  = v * att0[0]; q1  = v * att1[0];
            v = hp[1];  q0 += v * att0[1]; q1 += v * att1[1];
            v = hp[2];  q0 += v * att0[2]; q1 += v * att1[2];
            v = hp[11]; q0 += v * att0[3]; q1 += v * att1[3];
            v = hp[12]; q0 += v * att0[4]; q1 += v * att1[4];
            v = hp[13]; q0 += v * att0[5]; q1 += v * att1[5];
            v = hp[22]; q0 += v * att0[6]; q1 += v * att1[6];
            v = hp[23]; q0 += v * att0[7]; q1 += v * att1[7];
            v = hp[24]; q0 += v * att0[8]; q1 += v * att1[8];
            float2 rr; rr.x = q0; rr.y = q1;
            *(float2*)(ob + (size_t)(c0 + cc) * (HO * WO)) = rr;
        }
    }
}

extern "C" void kernel_launch(void* const* d_in, const int* in_sizes, int n_in,
                              void* d_out, int out_size, void* d_ws, size_t ws_size,
                              hipStream_t stream) {
    const float* guide = (const float*)d_in[0];
    const float* value = (const float*)d_in[1];
    const float* wconv = (const float*)d_in[2];
    const float* bconv = (const float*)d_in[3];
    float* outp = (float*)d_out;
    (void)in_sizes; (void)n_in; (void)out_size;

    const size_t att_bytes = (size_t)NB * KK * HO * WO * sizeof(float);  // 4.72 MB
    if (ws_size >= att_bytes) {
        float* attp = (float*)d_ws;
        la_att<<<dim3(512), dim3(256), 0, stream>>>(guide, wconv, bconv, attp);
        la_gather<<<dim3(1024), dim3(256), 0, stream>>>(value, attp, outp);
    } else {
        la_fused<<<dim3(NB * 8 * 8), dim3(128), 0, stream>>>(guide, value, wconv, bconv, outp);
    }
}

// Round 4
// 156.166 us; speedup vs baseline: 1.0803x; 1.0803x over previous
//
#include <hip/hip_runtime.h>

#define NB 8
#define CH 128
#define HV 64
#define WV 64
#define HO 128
#define WO 128
#define KK 9

// ======================= kernel A: attention (softmax) =======================
// v4 (unchanged): no LDS. Weights are wave-uniform -> scalar s_load, consumed
// as SGPR operands by v_fmac. 1 px/thread, 512 blocks x 256 thr (8 waves/CU).
// Residual (att += guide[:, :K]) folded by peeling channels 0..8.
__global__ __launch_bounds__(256)
void la_att(const float* __restrict__ guide,   // [8,128,128,128]
            const float* __restrict__ wconv,   // [9,128]
            const float* __restrict__ bconv,   // [9]
            float* __restrict__ att)           // [8,9,128,128] (workspace)
{
    const int tid = threadIdx.x;
    const int p  = blockIdx.x * 256 + tid;   // pixel index over (b, ho, wo)
    const int wo = p & 127;
    const int ho = (p >> 7) & 127;
    const int b  = p >> 14;

    const float* gpix = guide + ((size_t)b * CH) * (HO * WO) + ho * WO + wo;

    float a[KK];
    #pragma unroll
    for (int k = 0; k < KK; ++k)
        a[k] = bconv[k];                     // uniform -> s_load

    // ---- peeled channels 0..8: conv + residual (a[c] += g), k==c at compile time
    #pragma unroll
    for (int c = 0; c < KK; ++c) {
        float g = gpix[(size_t)c * (HO * WO)];
        #pragma unroll
        for (int k = 0; k < KK; ++k)
            a[k] += g * wconv[k * CH + c];   // uniform index -> SGPR operand
        a[c] += g;
    }

    // ---- channels 9..127: pure conv, weights via scalar pipe (no LDS)
    #pragma unroll 8
    for (int c = KK; c < CH; ++c) {
        float g = gpix[(size_t)c * (HO * WO)];
        #pragma unroll
        for (int k = 0; k < KK; ++k)
            a[k] += g * wconv[k * CH + c];
    }

    float m = a[0];
    #pragma unroll
    for (int k = 1; k < KK; ++k) m = fmaxf(m, a[k]);
    float s = 0.f;
    #pragma unroll
    for (int k = 0; k < KK; ++k) { a[k] = __expf(a[k] - m); s += a[k]; }
    float r = 1.0f / s;

    float* apix = att + ((size_t)b * KK) * (HO * WO) + ho * WO + wo;
    #pragma unroll
    for (int k = 0; k < KK; ++k)
        apix[(size_t)k * (HO * WO)] = a[k] * r;
}

// ======================= kernel B: weighted 3x3 gather =======================
// v6: LDS-free shuffle gather, latency-fixed.
//  - wave task = (b, value row h, 8-channel chunk): 8*64*16 = 8192 waves
//    = 2048 blocks x 256 thr (32 waves/CU requested, VGPR-capped ~24).
//  - ALL 24 value-row loads hoisted & issued first, then 18 att loads,
//    then shuffles/FMA/stores -> ~42 loads in flight per wave (was ~12).
//  - +-1 column neighbors via __shfl_up/down(.,1): edge-lane keep-own
//    semantics implement the replication clamp for free.
#define CHUNK 8
__global__ __launch_bounds__(256)
void la_gather(const float* __restrict__ value,  // [8,128,64,64]
               const float* __restrict__ att,    // [8,9,128,128]
               float* __restrict__ out)          // [8,128,128,128]
{
    const int tid   = threadIdx.x;
    const int lane  = tid & 63;                    // value column w
    const int wseq  = blockIdx.x * 4 + (tid >> 6); // 0..8191
    const int chunk = wseq & 15;                   // 8-channel chunk
    const int h     = (wseq >> 4) & 63;            // value row
    const int b     = wseq >> 10;                  // batch

    const int hm = (h > 0) ? h - 1 : 0;            // replication clamp, rows
    const int hp = (h < HV - 1) ? h + 1 : HV - 1;
    const float* vc  = value + ((size_t)b * CH + chunk * CHUNK) * (HV * WV) + lane;
    const float* prm = vc + hm * WV;
    const float* pr0 = vc + h  * WV;
    const float* prp = vc + hp * WV;

    // ---- phase 1: issue ALL value loads (24 independent) ----
    float vm[CHUNK], v0[CHUNK], vp[CHUNK];
    #pragma unroll
    for (int cc = 0; cc < CHUNK; ++cc) {
        vm[cc] = prm[(size_t)cc * (HV * WV)];
        v0[cc] = pr0[(size_t)cc * (HV * WV)];
        vp[cc] = prp[(size_t)cc * (HV * WV)];
    }

    // ---- phase 2: att for the 4 out px (2h,2h+1) x (2*lane, 2*lane+1) ----
    float a00[KK], a01[KK], a10[KK], a11[KK];
    {
        const float* ap = att + ((size_t)b * KK * HO + 2 * h) * WO + 2 * lane;
        #pragma unroll
        for (int k = 0; k < KK; ++k) {
            float2 r0 = *(const float2*)(ap + (size_t)k * (HO * WO));
            float2 r1 = *(const float2*)(ap + (size_t)k * (HO * WO) + WO);
            a00[k] = r0.x; a01[k] = r0.y;
            a10[k] = r1.x; a11[k] = r1.y;
        }
    }

    float* ob = out + (((size_t)b * CH + chunk * CHUNK) * HO + 2 * h) * WO + 2 * lane;

    // ---- phase 3: shuffles + FMA + stores ----
    #pragma unroll
    for (int cc = 0; cc < CHUNK; ++cc) {
        float tm = vm[cc], t0 = v0[cc], tp = vp[cc];
        // column neighbors; edge lanes keep own value == replication clamp
        float tmL = __shfl_up(tm, 1), tmR = __shfl_down(tm, 1);
        float t0L = __shfl_up(t0, 1), t0R = __shfl_down(t0, 1);
        float tpL = __shfl_up(tp, 1), tpR = __shfl_down(tp, 1);

        float s00 = tmL*a00[0] + tm*a00[1] + tmR*a00[2]
                  + t0L*a00[3] + t0*a00[4] + t0R*a00[5]
                  + tpL*a00[6] + tp*a00[7] + tpR*a00[8];
        float s01 = tmL*a01[0] + tm*a01[1] + tmR*a01[2]
                  + t0L*a01[3] + t0*a01[4] + t0R*a01[5]
                  + tpL*a01[6] + tp*a01[7] + tpR*a01[8];
        float s10 = tmL*a10[0] + tm*a10[1] + tmR*a10[2]
                  + t0L*a10[3] + t0*a10[4] + t0R*a10[5]
                  + tpL*a10[6] + tp*a10[7] + tpR*a10[8];
        float s11 = tmL*a11[0] + tm*a11[1] + tmR*a11[2]
                  + t0L*a11[3] + t0*a11[4] + t0R*a11[5]
                  + tpL*a11[6] + tp*a11[7] + tpR*a11[8];

        float* oc = ob + (size_t)cc * (HO * WO);
        float2 r0; r0.x = s00; r0.y = s01;
        float2 r1; r1.x = s10; r1.y = s11;
        *(float2*)oc        = r0;   // out row 2h
        *(float2*)(oc + WO) = r1;   // out row 2h+1
    }
}

// ================== fallback: proven single fused kernel (R1) ==================
#define CCH 8
__global__ __launch_bounds__(128)
void la_fused(const float* __restrict__ guide,
              const float* __restrict__ value,
              const float* __restrict__ wconv,
              const float* __restrict__ bconv,
              float* __restrict__ out)
{
    __shared__ float s_wT[CH * 12];
    __shared__ float s_haloF[CCH * 110];

    const int tid = threadIdx.x;
    const int blk = blockIdx.x;
    const int wt = blk & 7;
    const int ht = (blk >> 3) & 7;
    const int b  = blk >> 6;

    for (int i = tid; i < KK * CH; i += 128) {
        int k = i >> 7;
        int c = i & 127;
        s_wT[c * 12 + k] = wconv[i];
    }

    const int tlwp = tid & 7;
    const int tho  = tid >> 3;
    const int ho = ht * 16 + tho;
    const int wo = wt * 16 + tlwp * 2;

    const float* gpix = guide + (((size_t)b * CH) * HO + ho) * WO + wo;

    float att0[KK], att1[KK];
    #pragma unroll
    for (int k = 0; k < KK; ++k) {
        float2 g = *(const float2*)(gpix + (size_t)k * (HO * WO));
        float bc = bconv[k];
        att0[k] = bc + g.x;
        att1[k] = bc + g.y;
    }
    __syncthreads();

    #pragma unroll 4
    for (int c = 0; c < CH; ++c) {
        float2 g = *(const float2*)(gpix + (size_t)c * (HO * WO));
        const float4* wt4 = (const float4*)&s_wT[c * 12];
        float4 wa = wt4[0];
        float4 wb = wt4[1];
        float w8 = s_wT[c * 12 + 8];
        att0[0] += g.x * wa.x;  att1[0] += g.y * wa.x;
        att0[1] += g.x * wa.y;  att1[1] += g.y * wa.y;
        att0[2] += g.x * wa.z;  att1[2] += g.y * wa.z;
        att0[3] += g.x * wa.w;  att1[3] += g.y * wa.w;
        att0[4] += g.x * wb.x;  att1[4] += g.y * wb.x;
        att0[5] += g.x * wb.y;  att1[5] += g.y * wb.y;
        att0[6] += g.x * wb.z;  att1[6] += g.y * wb.z;
        att0[7] += g.x * wb.w;  att1[7] += g.y * wb.w;
        att0[8] += g.x * w8;    att1[8] += g.y * w8;
    }

    float m0 = att0[0], m1 = att1[0];
    #pragma unroll
    for (int k = 1; k < KK; ++k) { m0 = fmaxf(m0, att0[k]); m1 = fmaxf(m1, att1[k]); }
    float s0 = 0.f, s1 = 0.f;
    #pragma unroll
    for (int k = 0; k < KK; ++k) {
        att0[k] = __expf(att0[k] - m0); s0 += att0[k];
        att1[k] = __expf(att1[k] - m1); s1 += att1[k];
    }
    float r0 = 1.0f / s0, r1 = 1.0f / s1;
    #pragma unroll
    for (int k = 0; k < KK; ++k) { att0[k] *= r0; att1[k] *= r1; }

    const int h0 = ht * 8 - 1;
    const int w0 = wt * 8 - 1;
    const int lh = tho >> 1;
    const float* vb = value + (size_t)b * CH * (HV * WV);
    float* ob = out + (((size_t)b * CH) * HO + ho) * WO + wo;

    for (int c0 = 0; c0 < CH; c0 += CCH) {
        __syncthreads();
        for (int i = tid; i < CCH * 100; i += 128) {
            int cc = i / 100;
            int r  = i - cc * 100;
            int hr = r / 10;
            int wr = r - hr * 10;
            int hh = min(max(h0 + hr, 0), HV - 1);
            int ww = min(max(w0 + wr, 0), WV - 1);
            s_haloF[cc * 110 + hr * 11 + wr] =
                vb[(size_t)(c0 + cc) * (HV * WV) + hh * WV + ww];
        }
        __syncthreads();
        #pragma unroll
        for (int cc = 0; cc < CCH; ++cc) {
            const float* hp = &s_haloF[cc * 110 + lh * 11 + tlwp];
            float v, q0, q1;
            v = hp[0];  q0  = v * att0[0]; q1  = v * att1[0];
            v = hp[1];  q0 += v * att0[1]; q1 += v * att1[1];
            v = hp[2];  q0 += v * att0[2]; q1 += v * att1[2];
            v = hp[11]; q0 += v * att0[3]; q1 += v * att1[3];
            v = hp[12]; q0 += v * att0[4]; q1 += v * att1[4];
            v = hp[13]; q0 += v * att0[5]; q1 += v * att1[5];
            v = hp[22]; q0 += v * att0[6]; q1 += v * att1[6];
            v = hp[23]; q0 += v * att0[7]; q1 += v * att1[7];
            v = hp[24]; q0 += v * att0[8]; q1 += v * att1[8];
            float2 rr; rr.x = q0; rr.y = q1;
            *(float2*)(ob + (size_t)(c0 + cc) * (HO * WO)) = rr;
        }
    }
}

extern "C" void kernel_launch(void* const* d_in, const int* in_sizes, int n_in,
                              void* d_out, int out_size, void* d_ws, size_t ws_size,
                              hipStream_t stream) {
    const float* guide = (const float*)d_in[0];
    const float* value = (const float*)d_in[1];
    const float* wconv = (const float*)d_in[2];
    const float* bconv = (const float*)d_in[3];
    float* outp = (float*)d_out;
    (void)in_sizes; (void)n_in; (void)out_size;

    const size_t att_bytes = (size_t)NB * KK * HO * WO * sizeof(float);  // 4.72 MB
    if (ws_size >= att_bytes) {
        float* attp = (float*)d_ws;
        la_att<<<dim3(512), dim3(256), 0, stream>>>(guide, wconv, bconv, attp);
        la_gather<<<dim3(2048), dim3(256), 0, stream>>>(value, attp, outp);
    } else {
        la_fused<<<dim3(NB * 8 * 8), dim3(128), 0, stream>>>(guide, value, wconv, bconv, outp);
    }
}